// Round 4
// baseline (884.827 us; speedup 1.0000x reference)
//
#include <hip/hip_runtime.h>

#define IMG 256
#define TW 16
#define TH 8
#define TXN (IMG/TW)        // 16 tiles across
#define TYN (IMG/TH)        // 32 tiles down
#define TILES (TXN*TYN)     // 512 per batch
#define KCH 128             // faces per chunk
#define QCAP 65536
#define RBLOCKS 2048
#define BIGF 1e30f

__device__ __forceinline__ float ndc(int i) { return (2.0f*i + 1.0f - IMG) * (1.0f/IMG); }

// ---------------- init: zbuf = +inf bits, counters = 0 ------------------------
__global__ void k_init(unsigned int* __restrict__ zbuf, int nz,
                       int* __restrict__ cnts, int nc, int* __restrict__ ctrs) {
    int i = blockIdx.x * blockDim.x + threadIdx.x;
    int stride = gridDim.x * blockDim.x;
    for (int j = i; j < nz; j += stride) zbuf[j] = 0x7F800000u;  // +inf
    for (int j = i; j < nc; j += stride) cnts[j] = 0;
    if (i < 2) ctrs[i] = 0;   // [0]=work cursor, [1]=qcount
}

// ---------------- project vertices to NDC (u, v, z) ---------------------------
__global__ void k_project(const float* __restrict__ verts,
                          const float* __restrict__ Km,
                          const float* __restrict__ Rm,
                          const float* __restrict__ tm,
                          const float* __restrict__ dm,
                          float4* __restrict__ pv, int B, int V) {
    int i = blockIdx.x * blockDim.x + threadIdx.x;
    if (i >= B * V) return;
    int b = i / V;
    const float* R = Rm + b * 9;
    const float* K = Km + b * 9;
    const float* t = tm + b * 3;
    const float* d = dm + b * 5;
    float px = verts[3*i], py = verts[3*i+1], pz = verts[3*i+2];
    float x = R[0]*px + R[1]*py + R[2]*pz + t[0];
    float y = R[3]*px + R[4]*py + R[5]*pz + t[1];
    float z = R[6]*px + R[7]*py + R[8]*pz + t[2];
    float iz = 1.0f / (z + 1e-9f);
    float x_ = x * iz, y_ = y * iz;
    float k1 = d[0], k2 = d[1], p1 = d[2], p2 = d[3], k3 = d[4];
    float r2 = x_*x_ + y_*y_;
    float rad = 1.0f + k1*r2 + k2*r2*r2 + k3*r2*r2*r2;
    float xd = x_*rad + 2.0f*p1*x_*y_ + p2*(r2 + 2.0f*x_*x_);
    float yd = y_*rad + p1*(r2 + 2.0f*y_*y_) + 2.0f*p2*x_*y_;
    float u  = K[0]*xd + K[1]*yd + K[2];
    float vc = K[3]*xd + K[4]*yd + K[5];
    vc = 1024.0f - vc;
    u  = (u  - 512.0f) * (1.0f/512.0f);
    vc = (vc - 512.0f) * (1.0f/512.0f);
    pv[i] = make_float4(u, vc, z, 0.0f);
}

// conservative tile-vs-face test: max of each edge plane over tile rect corners
__device__ __forceinline__ bool tile_test(const float4& ca, const float4& cb, const float4& cc,
                                          float txlo, float txhi, float tylo, float tyhi) {
    float m0 = fmaxf(ca.x*txlo, ca.x*txhi) + fmaxf(ca.y*tylo, ca.y*tyhi) + cb.z;
    float m1 = fmaxf(ca.z*txlo, ca.z*txhi) + fmaxf(ca.w*tylo, ca.w*tyhi) + cb.w;
    float m2 = fmaxf(cb.x*txlo, cb.x*txhi) + fmaxf(cb.y*tylo, cb.y*tyhi) + cc.x;
    return fminf(fminf(m0, m1), m2) >= -1e-5f;
}

// ---------------- face setup + per-tile counts --------------------------------
// fd[3i+0]=ca=(P0x,P0y,P1x,P1y)  fd[3i+1]=cb=(P2x,P2y,A0,A1)
// fd[3i+2]=cc=(A2, -zix, -ziy, 10-zic)   [n3 = 10 - zinv as 4th plane]
// bb=(xmn,xmx,ymn,ymx)
__global__ void k_setup_count(const int* __restrict__ faces,
                              const float4* __restrict__ pv,
                              float4* __restrict__ fd, float4* __restrict__ bb,
                              int* __restrict__ cnts, int B, int V, int F) {
    int i = blockIdx.x * blockDim.x + threadIdx.x;
    if (i >= B * F) return;
    int b = i / F;
    int i0 = faces[3*i], i1 = faces[3*i+1], i2 = faces[3*i+2];
    float4 v0 = pv[b*V + i0], v1 = pv[b*V + i1], v2 = pv[b*V + i2];
    float x0=v0.x, y0=v0.y, z0=v0.z;
    float x1=v1.x, y1=v1.y, z1=v1.z;
    float x2=v2.x, y2=v2.y, z2=v2.z;
    float denom = (y1-y2)*(x0-x2) + (x2-x1)*(y0-y2);
    bool ok = (fabsf(denom) > 1e-8f) && (z0 > 1e-8f) && (z1 > 1e-8f) && (z2 > 1e-8f);
    if (!ok) { bb[i] = make_float4(3e38f, -3e38f, 3e38f, -3e38f); return; }
    float s = (denom > 0.0f) ? 1.0f : -1.0f;
    float absd = fabsf(denom);
    float P0x = s*(y1-y2), P0y = s*(x2-x1);
    float P1x = s*(y2-y0), P1y = s*(x0-x2);
    float P2x = -(P0x + P1x), P2y = -(P0y + P1y);
    float A0 = -(P0x*x2 + P0y*y2);
    float A1 = -(P1x*x2 + P1y*y2);
    float A2 = absd - A0 - A1;
    float ia  = 1.0f / absd;
    float rz0 = ia / z0, rz1 = ia / z1, rz2 = ia / z2;
    float zix = P0x*rz0 + P1x*rz1 + P2x*rz2;
    float ziy = P0y*rz0 + P1y*rz1 + P2y*rz2;
    float zic = A0*rz0 + A1*rz1 + A2*rz2;
    float xmn = fminf(x0, fminf(x1, x2)) - 1e-4f;
    float xmx = fmaxf(x0, fmaxf(x1, x2)) + 1e-4f;
    float ymn = fminf(y0, fminf(y1, y2)) - 1e-4f;
    float ymx = fmaxf(y0, fmaxf(y1, y2)) + 1e-4f;
    float4 ca = make_float4(P0x, P0y, P1x, P1y);
    float4 cb = make_float4(P2x, P2y, A0, A1);
    float4 cc = make_float4(A2, -zix, -ziy, 10.0f - zic);
    fd[(size_t)i*3 + 0] = ca;
    fd[(size_t)i*3 + 1] = cb;
    fd[(size_t)i*3 + 2] = cc;
    bb[i] = make_float4(xmn, xmx, ymn, ymx);
    // pixel-index bbox -> tile range
    int clo = max(0, (int)ceilf (xmn*128.0f + 127.5f));
    int chi = min(IMG-1, (int)floorf(xmx*128.0f + 127.5f));
    int rlo = max(0, (int)ceilf (ymn*128.0f + 127.5f));
    int rhi = min(IMG-1, (int)floorf(ymx*128.0f + 127.5f));
    if (clo > chi || rlo > rhi) return;
    for (int ty = rlo >> 3; ty <= (rhi >> 3); ++ty) {
        float tylo = ndc(ty*TH), tyhi = ndc(ty*TH + TH - 1);
        for (int tx = clo >> 4; tx <= (chi >> 4); ++tx) {
            float txlo = ndc(tx*TW), txhi = ndc(tx*TW + TW - 1);
            if (tile_test(ca, cb, cc, txlo, txhi, tylo, tyhi))
                atomicAdd(&cnts[b*TILES + ty*TXN + tx], 1);
        }
    }
}

// ---------------- scan (exclusive) + queue build ------------------------------
__global__ __launch_bounds__(1024) void k_scan_queue(const int* __restrict__ cnts,
                                                     int* __restrict__ offs, int* __restrict__ cur,
                                                     int4* __restrict__ queue, int* __restrict__ qcount,
                                                     int NB, int binCap) {
    __shared__ int sT[1024];
    int t = threadIdx.x;
    int per = (NB + 1023) >> 10;
    int lo = t * per, hi = min(lo + per, NB);
    int sum = 0;
    for (int j = lo; j < hi; ++j) sum += cnts[j];
    sT[t] = sum;
    __syncthreads();
    for (int d2 = 1; d2 < 1024; d2 <<= 1) {
        int v = (t >= d2) ? sT[t - d2] : 0;
        __syncthreads();
        sT[t] += v;
        __syncthreads();
    }
    int run = (t > 0) ? sT[t-1] : 0;
    for (int j = lo; j < hi; ++j) {
        offs[j] = run; cur[j] = run;
        int n = cnts[j];
        for (int s2 = 0; s2 < n; s2 += KCH) {
            int len = min(KCH, n - s2);
            if (run + s2 + len <= binCap) {
                int qi = atomicAdd(qcount, 1);
                if (qi < QCAP) queue[qi] = make_int4(j, run + s2, len, 0);
            }
        }
        run += n;
    }
    if (lo < NB && hi == NB) offs[NB] = sT[1023];
}

// ---------------- scatter face ids into bins ----------------------------------
__global__ void k_scatter(const float4* __restrict__ fd, const float4* __restrict__ bb,
                          int* __restrict__ cur, int* __restrict__ bins, int binCap,
                          int B, int F) {
    int i = blockIdx.x * blockDim.x + threadIdx.x;
    if (i >= B * F) return;
    int b = i / F;
    float4 box = bb[i];
    int clo = max(0, (int)ceilf (box.x*128.0f + 127.5f));
    int chi = min(IMG-1, (int)floorf(box.y*128.0f + 127.5f));
    int rlo = max(0, (int)ceilf (box.z*128.0f + 127.5f));
    int rhi = min(IMG-1, (int)floorf(box.w*128.0f + 127.5f));
    if (clo > chi || rlo > rhi) return;
    float4 ca = fd[(size_t)i*3 + 0];
    float4 cb = fd[(size_t)i*3 + 1];
    float4 cc = fd[(size_t)i*3 + 2];
    for (int ty = rlo >> 3; ty <= (rhi >> 3); ++ty) {
        float tylo = ndc(ty*TH), tyhi = ndc(ty*TH + TH - 1);
        for (int tx = clo >> 4; tx <= (chi >> 4); ++tx) {
            float txlo = ndc(tx*TW), txhi = ndc(tx*TW + TW - 1);
            if (tile_test(ca, cb, cc, txlo, txhi, tylo, tyhi)) {
                int idx = atomicAdd(&cur[b*TILES + ty*TXN + tx], 1);
                if (idx < binCap) bins[idx] = i;   // global face row (b*F+f)
            }
        }
    }
}

// ---------------- persistent binned raster ------------------------------------
// wave-per-face over a 16x8 tile (2 px/lane); track min n3 (= max zinv); merge
// the 4 waves in LDS; atomicMin into global z-buffer (uint-monotone, init +inf).
__global__ __launch_bounds__(256) void k_raster_bins(const float4* __restrict__ fd,
                                                     const int* __restrict__ bins,
                                                     const int4* __restrict__ queue,
                                                     const int* __restrict__ qcount_p,
                                                     int* __restrict__ cursor,
                                                     unsigned int* __restrict__ zbuf) {
    __shared__ int sId[KCH];
    __shared__ float4 sF[KCH*3];
    __shared__ float zs[4*TW*TH];
    __shared__ int sPop;
    int tid = threadIdx.x, lane = tid & 63, wave = tid >> 6;
    int qn = min(*qcount_p, QCAP);
    while (true) {
        if (tid == 0) sPop = atomicAdd(cursor, 1);
        __syncthreads();
        int wi = sPop;
        if (wi >= qn) break;
        int4 it = queue[wi];
        int bin = it.x, start = it.y, cnt = it.z;
        if (tid < cnt) sId[tid] = bins[start + tid];
        __syncthreads();
        if (tid < cnt) {
            size_t fo = (size_t)sId[tid] * 3;
            sF[3*tid]   = fd[fo];
            sF[3*tid+1] = fd[fo+1];
            sF[3*tid+2] = fd[fo+2];
        }
        __syncthreads();
        int b = bin / TILES, t = bin % TILES;
        int tx = (t & (TXN-1)) * TW, ty = (t >> 4) * TH;
        int rrow = ty + (lane >> 3), colb = tx + (lane & 7) * 2;
        float yp = ndc(rrow), xp0 = ndc(colb), xp1 = ndc(colb + 1);
        float m0 = BIGF, m1 = BIGF;
        for (int k = wave; k < cnt; k += 4) {
            float4 ca = sF[3*k], cb = sF[3*k+1], cc = sF[3*k+2];
            float e0 = fmaf(ca.y, yp, cb.z);
            float e1 = fmaf(ca.w, yp, cb.w);
            float e2 = fmaf(cb.y, yp, cc.x);
            float e3 = fmaf(cc.z, yp, cc.w);
            float n0 = fmaf(ca.x, xp0, e0);
            float n1 = fmaf(ca.z, xp0, e1);
            float n2 = fmaf(cb.x, xp0, e2);
            float n3 = fmaf(cc.y, xp0, e3);
            float mn = fminf(fminf(fminf(n0, n1), n2), n3);
            m0 = fminf(m0, (mn >= 0.0f) ? n3 : BIGF);
            n0 = fmaf(ca.x, xp1, e0);
            n1 = fmaf(ca.z, xp1, e1);
            n2 = fmaf(cb.x, xp1, e2);
            n3 = fmaf(cc.y, xp1, e3);
            mn = fminf(fminf(fminf(n0, n1), n2), n3);
            m1 = fminf(m1, (mn >= 0.0f) ? n3 : BIGF);
        }
        int p = (lane >> 3) * TW + (lane & 7) * 2;
        zs[wave*128 + p]     = m0;
        zs[wave*128 + p + 1] = m1;
        __syncthreads();
        if (tid < 128) {
            float mm = fminf(fminf(zs[tid], zs[128+tid]), fminf(zs[256+tid], zs[384+tid]));
            if (mm < 0.5f * BIGF) {
                int py = ty + (tid >> 4), px = tx + (tid & 15);
                atomicMin(&zbuf[(size_t)b*(IMG*IMG) + py*IMG + px], __float_as_uint(mm));
            }
        }
        __syncthreads();
    }
}

// ---------------- resolve: depth = 1/(10-m), row flip -------------------------
__global__ void k_resolve(const unsigned int* __restrict__ zbuf, float* __restrict__ out, int B) {
    int i = blockIdx.x * blockDim.x + threadIdx.x;
    int n = B * IMG * IMG;
    if (i >= n) return;
    int b = i / (IMG*IMG);
    int rem = i - b * (IMG*IMG);
    int r = rem >> 8, c = rem & 255;
    unsigned int u = zbuf[(size_t)b*(IMG*IMG) + (IMG-1-r)*IMG + c];
    float m = __uint_as_float(u);
    // valid needs zinv=10-m > 0.01 (zp<far); background (+inf) also -> far
    out[i] = (m < 9.99f) ? 1.0f / (10.0f - m) : 100.0f;
}

// ---------------- fallback: brute row-stripe direct (tiny ws only) ------------
__global__ __launch_bounds__(256) void k_brute(const float4* __restrict__ fd,
                                               const float4* __restrict__ bb,
                                               float* __restrict__ out, int B, int F) {
    int bid = blockIdx.x;
    int stripe = bid % 64, b = bid / 64;
    int tid = threadIdx.x, lane = tid & 63, wave = tid >> 6;
    int row = stripe * 4 + wave, colb = lane * 4;
    float yp = ndc(row);
    float xp[4]; float m[4];
    #pragma unroll
    for (int j = 0; j < 4; ++j) { xp[j] = ndc(colb + j); m[j] = BIGF; }
    const float4* fbb = bb + (size_t)b * F;
    const float4* ffd = fd + (size_t)b * F * 3;
    for (int f = 0; f < F; ++f) {
        float4 box = fbb[f];
        if (box.z > yp || box.w < yp) continue;
        float4 ca = ffd[3*f], cb = ffd[3*f+1], cc = ffd[3*f+2];
        float e0 = fmaf(ca.y, yp, cb.z);
        float e1 = fmaf(ca.w, yp, cb.w);
        float e2 = fmaf(cb.y, yp, cc.x);
        float e3 = fmaf(cc.z, yp, cc.w);
        #pragma unroll
        for (int j = 0; j < 4; ++j) {
            float n0 = fmaf(ca.x, xp[j], e0);
            float n1 = fmaf(ca.z, xp[j], e1);
            float n2 = fmaf(cb.x, xp[j], e2);
            float n3 = fmaf(cc.y, xp[j], e3);
            float mn = fminf(fminf(fminf(n0, n1), n2), n3);
            m[j] = fminf(m[j], (mn >= 0.0f) ? n3 : BIGF);
        }
    }
    size_t o = (size_t)b*(IMG*IMG) + (size_t)(IMG-1-row)*IMG + colb;
    float4 r;
    r.x = (m[0] < 9.99f) ? 1.0f/(10.0f-m[0]) : 100.0f;
    r.y = (m[1] < 9.99f) ? 1.0f/(10.0f-m[1]) : 100.0f;
    r.z = (m[2] < 9.99f) ? 1.0f/(10.0f-m[2]) : 100.0f;
    r.w = (m[3] < 9.99f) ? 1.0f/(10.0f-m[3]) : 100.0f;
    *(float4*)(out + o) = r;
}

extern "C" void kernel_launch(void* const* d_in, const int* in_sizes, int n_in,
                              void* d_out, int out_size, void* d_ws, size_t ws_size,
                              hipStream_t stream) {
    const float* verts = (const float*)d_in[0];
    const int*   faces = (const int*)d_in[1];
    const float* Km    = (const float*)d_in[2];
    const float* Rm    = (const float*)d_in[3];
    const float* tm    = (const float*)d_in[4];
    const float* dm    = (const float*)d_in[5];
    float* out = (float*)d_out;

    int B = in_sizes[2] / 9;
    int V = in_sizes[0] / (3 * B);
    int F = in_sizes[1] / (3 * B);
    int NB = B * TILES;
    int nz = B * IMG * IMG;

    char* ws = (char*)d_ws;
    size_t al = 255;
    size_t o_pv   = 0;
    size_t o_fd   = (o_pv + (size_t)B*V*16 + al) & ~al;
    size_t o_bb   = (o_fd + (size_t)B*F*48 + al) & ~al;
    size_t o_cnt  = (o_bb + (size_t)B*F*16 + al) & ~al;
    size_t o_offs = (o_cnt + (size_t)NB*4 + al) & ~al;
    size_t o_cur  = (o_offs + (size_t)(NB+1)*4 + al) & ~al;
    size_t o_ctr  = (o_cur + (size_t)NB*4 + al) & ~al;
    size_t o_zb   = (o_ctr + 256 + al) & ~al;
    size_t o_q    = (o_zb + (size_t)nz*4 + al) & ~al;
    size_t o_bins = (o_q + (size_t)QCAP*16 + al) & ~al;

    float4* pv   = (float4*)(ws + o_pv);
    float4* fd   = (float4*)(ws + o_fd);
    float4* bbp  = (float4*)(ws + o_bb);
    int*    cnts = (int*)(ws + o_cnt);
    int*    offs = (int*)(ws + o_offs);
    int*    cur  = (int*)(ws + o_cur);
    int*    ctrs = (int*)(ws + o_ctr);
    unsigned int* zb = (unsigned int*)(ws + o_zb);
    int4*   queue = (int4*)(ws + o_q);
    int*    bins = (int*)(ws + o_bins);
    long long binCapLL = (ws_size > o_bins) ? (long long)((ws_size - o_bins) / 4) : 0;
    int binCap = (binCapLL > 2147000000LL) ? 2147000000 : (int)binCapLL;

    const int thr = 256;
    k_project<<<(B*V + thr-1)/thr, thr, 0, stream>>>(verts, Km, Rm, tm, dm, pv, B, V);

    if (binCap >= B * F * 2) {
        k_init<<<512, thr, 0, stream>>>(zb, nz, cnts, NB, ctrs);
        k_setup_count<<<(B*F + thr-1)/thr, thr, 0, stream>>>(faces, pv, fd, bbp, cnts, B, V, F);
        k_scan_queue<<<1, 1024, 0, stream>>>(cnts, offs, cur, queue, &ctrs[1], NB, binCap);
        k_scatter<<<(B*F + thr-1)/thr, thr, 0, stream>>>(fd, bbp, cur, bins, binCap, B, F);
        k_raster_bins<<<RBLOCKS, thr, 0, stream>>>(fd, bins, queue, &ctrs[1], &ctrs[0], zb);
        k_resolve<<<(nz + thr-1)/thr, thr, 0, stream>>>(zb, out, B);
    } else {
        // tiny workspace fallback: brute direct raster (needs only fd+bb)
        k_setup_count<<<(B*F + thr-1)/thr, thr, 0, stream>>>(faces, pv, fd, bbp, cnts, B, V, F);
        k_brute<<<B*64, thr, 0, stream>>>(fd, bbp, out, B, F);
    }
}

// Round 5
// 316.413 us; speedup vs baseline: 2.7964x; 2.7964x over previous
//
#include <hip/hip_runtime.h>

#define IMG 256
#define TW 32
#define TH 32
#define TXN (IMG/TW)        // 8 tiles across
#define TYN (IMG/TH)        // 8 tiles down
#define TILES (TXN*TYN)     // 64
#define NSPLIT 64           // face splits per tile
#define RBLOCKS 2048
#define BIGF 1e30f

__device__ __forceinline__ float ndc(int i) { return (2.0f*i + 1.0f - IMG) * (1.0f/IMG); }

// center-out ring walk over the 8x8 tile grid: rank 0..63 -> (tx,ty)
__device__ __forceinline__ void rank_to_tile(int rank, int& tx, int& ty) {
    int k, base;
    if (rank < 4)       { k = 0; base = 0;  }
    else if (rank < 16) { k = 1; base = 4;  }
    else if (rank < 36) { k = 2; base = 16; }
    else                { k = 3; base = 36; }
    int j = rank - base;
    int s = 2*k + 2;          // ring side
    int seg = j / (s - 1);
    int off = j - seg * (s - 1);
    int lo = 3 - k, hi = 4 + k;
    if      (seg == 0) { tx = lo + off; ty = lo; }
    else if (seg == 1) { tx = hi;       ty = lo + off; }
    else if (seg == 2) { tx = hi - off; ty = hi; }
    else               { tx = lo;       ty = hi - off; }
}

// ---------------- init: zbuf = +inf bits, cursor = 0 --------------------------
__global__ void k_init(unsigned int* __restrict__ zbuf, int nz, int* __restrict__ ctrs) {
    int i = blockIdx.x * blockDim.x + threadIdx.x;
    int stride = gridDim.x * blockDim.x;
    for (int j = i; j < nz; j += stride) zbuf[j] = 0x7F800000u;  // +inf
    if (i == 0) ctrs[0] = 0;
}

// ---------------- project vertices to NDC (u, v, z) ---------------------------
__global__ void k_project(const float* __restrict__ verts,
                          const float* __restrict__ Km,
                          const float* __restrict__ Rm,
                          const float* __restrict__ tm,
                          const float* __restrict__ dm,
                          float4* __restrict__ pv, int B, int V) {
    int i = blockIdx.x * blockDim.x + threadIdx.x;
    if (i >= B * V) return;
    int b = i / V;
    const float* R = Rm + b * 9;
    const float* K = Km + b * 9;
    const float* t = tm + b * 3;
    const float* d = dm + b * 5;
    float px = verts[3*i], py = verts[3*i+1], pz = verts[3*i+2];
    float x = R[0]*px + R[1]*py + R[2]*pz + t[0];
    float y = R[3]*px + R[4]*py + R[5]*pz + t[1];
    float z = R[6]*px + R[7]*py + R[8]*pz + t[2];
    float iz = 1.0f / (z + 1e-9f);
    float x_ = x * iz, y_ = y * iz;
    float k1 = d[0], k2 = d[1], p1 = d[2], p2 = d[3], k3 = d[4];
    float r2 = x_*x_ + y_*y_;
    float rad = 1.0f + k1*r2 + k2*r2*r2 + k3*r2*r2*r2;
    float xd = x_*rad + 2.0f*p1*x_*y_ + p2*(r2 + 2.0f*x_*x_);
    float yd = y_*rad + p1*(r2 + 2.0f*y_*y_) + 2.0f*p2*x_*y_;
    float u  = K[0]*xd + K[1]*yd + K[2];
    float vc = K[3]*xd + K[4]*yd + K[5];
    vc = 1024.0f - vc;
    u  = (u  - 512.0f) * (1.0f/512.0f);
    vc = (vc - 512.0f) * (1.0f/512.0f);
    pv[i] = make_float4(u, vc, z, 0.0f);
}

// ---------------- face setup ---------------------------------------------------
// fd[3i+0]=ca=(P0x,P0y,P1x,P1y)  fd[3i+1]=cb=(P2x,P2y,A0,A1)
// fd[3i+2]=cc=(A2, -zix, -ziy, 10-zic)   [n3 = 10 - zinv as 4th plane]
// bb=(xmn,xmx,ymn,ymx); invalid -> always-fail bbox
__global__ void k_facesetup(const int* __restrict__ faces,
                            const float4* __restrict__ pv,
                            float4* __restrict__ fd, float4* __restrict__ bb,
                            int B, int V, int F) {
    int i = blockIdx.x * blockDim.x + threadIdx.x;
    if (i >= B * F) return;
    int b = i / F;
    int i0 = faces[3*i], i1 = faces[3*i+1], i2 = faces[3*i+2];
    float4 v0 = pv[b*V + i0], v1 = pv[b*V + i1], v2 = pv[b*V + i2];
    float x0=v0.x, y0=v0.y, z0=v0.z;
    float x1=v1.x, y1=v1.y, z1=v1.z;
    float x2=v2.x, y2=v2.y, z2=v2.z;
    float denom = (y1-y2)*(x0-x2) + (x2-x1)*(y0-y2);
    bool ok = (fabsf(denom) > 1e-8f) && (z0 > 1e-8f) && (z1 > 1e-8f) && (z2 > 1e-8f);
    if (!ok) { bb[i] = make_float4(3e38f, -3e38f, 3e38f, -3e38f); return; }
    float s = (denom > 0.0f) ? 1.0f : -1.0f;
    float absd = fabsf(denom);
    float P0x = s*(y1-y2), P0y = s*(x2-x1);
    float P1x = s*(y2-y0), P1y = s*(x0-x2);
    float P2x = -(P0x + P1x), P2y = -(P0y + P1y);
    float A0 = -(P0x*x2 + P0y*y2);
    float A1 = -(P1x*x2 + P1y*y2);
    float A2 = absd - A0 - A1;
    float ia  = 1.0f / absd;
    float rz0 = ia / z0, rz1 = ia / z1, rz2 = ia / z2;
    float zix = P0x*rz0 + P1x*rz1 + P2x*rz2;
    float ziy = P0y*rz0 + P1y*rz1 + P2y*rz2;
    float zic = A0*rz0 + A1*rz1 + A2*rz2;
    fd[(size_t)i*3 + 0] = make_float4(P0x, P0y, P1x, P1y);
    fd[(size_t)i*3 + 1] = make_float4(P2x, P2y, A0, A1);
    fd[(size_t)i*3 + 2] = make_float4(A2, -zix, -ziy, 10.0f - zic);
    bb[i] = make_float4(fminf(x0, fminf(x1, x2)) - 1e-4f,
                        fmaxf(x0, fmaxf(x1, x2)) + 1e-4f,
                        fminf(y0, fminf(y1, y2)) - 1e-4f,
                        fmaxf(y0, fmaxf(y1, y2)) + 1e-4f);
}

// conservative tile-vs-face test: max of each edge plane over tile rect corners
__device__ __forceinline__ bool tile_test(const float4& ca, const float4& cb, const float4& cc,
                                          float txlo, float txhi, float tylo, float tyhi) {
    float m0 = fmaxf(ca.x*txlo, ca.x*txhi) + fmaxf(ca.y*tylo, ca.y*tyhi) + cb.z;
    float m1 = fmaxf(ca.z*txlo, ca.z*txhi) + fmaxf(ca.w*tylo, ca.w*tyhi) + cb.w;
    float m2 = fmaxf(cb.x*txlo, cb.x*txhi) + fmaxf(cb.y*tylo, cb.y*tyhi) + cc.x;
    return fminf(fminf(m0, m1), m2) >= -1e-5f;
}

// ---------------- persistent work-stealing raster ------------------------------
// item = (tile-rank [center-out], batch, face-split); ballot-compact survivors
// into LDS; 4 waves cover the 32x32 tile (8 rows each, 4 px/lane); merge via
// fire-and-forget atomicMin (uint-monotone on n3 >= 0, zbuf init +inf).
__global__ __launch_bounds__(256) void k_raster(const float4* __restrict__ fd,
                                                const float4* __restrict__ bb,
                                                int* __restrict__ cursor,
                                                unsigned int* __restrict__ zbuf,
                                                int B, int F) {
    __shared__ float4 sA[257], sB[257], sC[257];
    __shared__ int s_cnt[4];
    __shared__ int sPop;
    int tid = threadIdx.x, lane = tid & 63, wave = tid >> 6;
    int per = B * NSPLIT;
    int nitems = TILES * per;
    while (true) {
        if (tid == 0) sPop = atomicAdd(cursor, 1);
        __syncthreads();
        int wi = sPop;
        if (wi >= nitems) break;
        int rank = wi / per;
        int rem  = wi - rank * per;
        int b = rem % B;
        int sp = rem / B;
        int tx, ty;
        rank_to_tile(rank, tx, ty);
        int row = ty*TH + wave*8 + (lane >> 3);
        int col = tx*TW + (lane & 7) * 4;
        float yp = ndc(row);
        float xp[4];
        #pragma unroll
        for (int j = 0; j < 4; ++j) xp[j] = ndc(col + j);
        float txlo = ndc(tx*TW), txhi = ndc(tx*TW + TW - 1);
        float tylo = ndc(ty*TH), tyhi = ndc(ty*TH + TH - 1);
        int f_begin = (sp * F) / NSPLIT, f_end = ((sp+1) * F) / NSPLIT;
        float m[4] = {BIGF, BIGF, BIGF, BIGF};

        for (int g0 = f_begin; g0 < f_end; g0 += 256) {
            int f = g0 + tid;
            bool pass = false;
            float4 ra, rb, rc;
            if (f < f_end) {
                size_t gi = (size_t)b * F + f;
                float4 box = bb[gi];
                pass = !(box.x > txhi || box.y < txlo || box.z > tyhi || box.w < tylo);
                if (pass) {
                    ra = fd[gi*3]; rb = fd[gi*3+1]; rc = fd[gi*3+2];
                    pass = tile_test(ra, rb, rc, txlo, txhi, tylo, tyhi);
                }
            }
            unsigned long long mk = __ballot(pass);
            int prefix = __popcll(mk & ((1ull << lane) - 1ull));
            if (lane == 0) s_cnt[wave] = __popcll(mk);
            __syncthreads();
            int base = 0;
            #pragma unroll
            for (int w = 0; w < 4; ++w) base += (w < wave) ? s_cnt[w] : 0;
            int total = s_cnt[0] + s_cnt[1] + s_cnt[2] + s_cnt[3];
            if (pass) {
                int slot = base + prefix;
                sA[slot] = ra;
                sB[slot] = rb;
                sC[slot] = rc;
            }
            __syncthreads();
            if (total > 0) {
                float4 ca = sA[0], cb = sB[0], cc = sC[0];
                for (int i = 0; i < total; ++i) {
                    float4 na = sA[i+1], nb = sB[i+1], nc = sC[i+1];  // prefetch
                    float e0 = fmaf(ca.y, yp, cb.z);
                    float e1 = fmaf(ca.w, yp, cb.w);
                    float e2 = fmaf(cb.y, yp, cc.x);
                    float e3 = fmaf(cc.z, yp, cc.w);
                    #pragma unroll
                    for (int j = 0; j < 4; ++j) {
                        float n0 = fmaf(ca.x, xp[j], e0);
                        float n1 = fmaf(ca.z, xp[j], e1);
                        float n2 = fmaf(cb.x, xp[j], e2);
                        float n3 = fmaf(cc.y, xp[j], e3);
                        float mn = fminf(fminf(fminf(n0, n1), n2), n3);
                        m[j] = fminf(m[j], (mn >= 0.0f) ? n3 : BIGF);
                    }
                    ca = na; cb = nb; cc = nc;
                }
            }
            __syncthreads();
        }
        size_t zo = (size_t)b * (IMG*IMG) + (size_t)row * IMG + col;
        #pragma unroll
        for (int j = 0; j < 4; ++j)
            if (m[j] < 9.99f) atomicMin(&zbuf[zo + j], __float_as_uint(m[j]));
    }
}

// ---------------- resolve: depth = 1/(10-m), row flip -------------------------
__global__ void k_resolve(const unsigned int* __restrict__ zbuf, float* __restrict__ out, int B) {
    int i = blockIdx.x * blockDim.x + threadIdx.x;
    int n = B * IMG * IMG;
    if (i >= n) return;
    int b = i / (IMG*IMG);
    int rem = i - b * (IMG*IMG);
    int r = rem >> 8, c = rem & 255;
    unsigned int u = zbuf[(size_t)b*(IMG*IMG) + (IMG-1-r)*IMG + c];
    float m = __uint_as_float(u);
    out[i] = (m < 9.99f) ? 1.0f / (10.0f - m) : 100.0f;
}

// ---------------- fallback: brute row-stripe direct (tiny ws only) ------------
__global__ __launch_bounds__(256) void k_brute(const float4* __restrict__ fd,
                                               const float4* __restrict__ bb,
                                               float* __restrict__ out, int B, int F) {
    int bid = blockIdx.x;
    int stripe = bid % 64, b = bid / 64;
    int tid = threadIdx.x, lane = tid & 63, wave = tid >> 6;
    int row = stripe * 4 + wave, colb = lane * 4;
    float yp = ndc(row);
    float xp[4]; float m[4];
    #pragma unroll
    for (int j = 0; j < 4; ++j) { xp[j] = ndc(colb + j); m[j] = BIGF; }
    const float4* fbb = bb + (size_t)b * F;
    const float4* ffd = fd + (size_t)b * F * 3;
    for (int f = 0; f < F; ++f) {
        float4 box = fbb[f];
        if (box.z > yp || box.w < yp) continue;
        float4 ca = ffd[3*f], cb = ffd[3*f+1], cc = ffd[3*f+2];
        float e0 = fmaf(ca.y, yp, cb.z);
        float e1 = fmaf(ca.w, yp, cb.w);
        float e2 = fmaf(cb.y, yp, cc.x);
        float e3 = fmaf(cc.z, yp, cc.w);
        #pragma unroll
        for (int j = 0; j < 4; ++j) {
            float n0 = fmaf(ca.x, xp[j], e0);
            float n1 = fmaf(ca.z, xp[j], e1);
            float n2 = fmaf(cb.x, xp[j], e2);
            float n3 = fmaf(cc.y, xp[j], e3);
            float mn = fminf(fminf(fminf(n0, n1), n2), n3);
            m[j] = fminf(m[j], (mn >= 0.0f) ? n3 : BIGF);
        }
    }
    size_t o = (size_t)b*(IMG*IMG) + (size_t)(IMG-1-row)*IMG + colb;
    float4 r;
    r.x = (m[0] < 9.99f) ? 1.0f/(10.0f-m[0]) : 100.0f;
    r.y = (m[1] < 9.99f) ? 1.0f/(10.0f-m[1]) : 100.0f;
    r.z = (m[2] < 9.99f) ? 1.0f/(10.0f-m[2]) : 100.0f;
    r.w = (m[3] < 9.99f) ? 1.0f/(10.0f-m[3]) : 100.0f;
    *(float4*)(out + o) = r;
}

extern "C" void kernel_launch(void* const* d_in, const int* in_sizes, int n_in,
                              void* d_out, int out_size, void* d_ws, size_t ws_size,
                              hipStream_t stream) {
    const float* verts = (const float*)d_in[0];
    const int*   faces = (const int*)d_in[1];
    const float* Km    = (const float*)d_in[2];
    const float* Rm    = (const float*)d_in[3];
    const float* tm    = (const float*)d_in[4];
    const float* dm    = (const float*)d_in[5];
    float* out = (float*)d_out;

    int B = in_sizes[2] / 9;
    int V = in_sizes[0] / (3 * B);
    int F = in_sizes[1] / (3 * B);
    int nz = B * IMG * IMG;

    char* ws = (char*)d_ws;
    size_t al = 255;
    size_t o_pv  = 0;
    size_t o_fd  = (o_pv + (size_t)B*V*16 + al) & ~al;
    size_t o_bb  = (o_fd + (size_t)B*F*48 + al) & ~al;
    size_t o_ctr = (o_bb + (size_t)B*F*16 + al) & ~al;
    size_t o_zb  = (o_ctr + 256 + al) & ~al;
    size_t need  = o_zb + (size_t)nz*4;
    size_t need_brute = o_ctr;

    float4* pv  = (float4*)(ws + o_pv);
    float4* fd  = (float4*)(ws + o_fd);
    float4* bbp = (float4*)(ws + o_bb);
    int*    ctr = (int*)(ws + o_ctr);
    unsigned int* zb = (unsigned int*)(ws + o_zb);

    const int thr = 256;
    k_project<<<(B*V + thr-1)/thr, thr, 0, stream>>>(verts, Km, Rm, tm, dm, pv, B, V);
    if (ws_size >= need) {
        k_init<<<256, thr, 0, stream>>>(zb, nz, ctr);
        k_facesetup<<<(B*F + thr-1)/thr, thr, 0, stream>>>(faces, pv, fd, bbp, B, V, F);
        k_raster<<<RBLOCKS, thr, 0, stream>>>(fd, bbp, ctr, zb, B, F);
        k_resolve<<<(nz + thr-1)/thr, thr, 0, stream>>>(zb, out, B);
    } else if (ws_size >= need_brute) {
        k_facesetup<<<(B*F + thr-1)/thr, thr, 0, stream>>>(faces, pv, fd, bbp, B, V, F);
        k_brute<<<B*64, thr, 0, stream>>>(fd, bbp, out, B, F);
    }
}

// Round 6
// 204.096 us; speedup vs baseline: 4.3353x; 1.5503x over previous
//
#include <hip/hip_runtime.h>

#define IMG 256
#define TW 32
#define TH 32
#define TXN (IMG/TW)        // 8 tiles across
#define TYN (IMG/TH)        // 8 tiles down
#define TILES (TXN*TYN)     // 64
#define NSPLIT 32           // face splits per tile
#define RBLOCKS 2048
#define BIGF 1e30f

__device__ __forceinline__ float ndc(int i) { return (2.0f*i + 1.0f - IMG) * (1.0f/IMG); }

// center-out ring walk over the 8x8 tile grid: rank 0..63 -> (tx,ty)
__device__ __forceinline__ void rank_to_tile(int rank, int& tx, int& ty) {
    int k, base;
    if (rank < 4)       { k = 0; base = 0;  }
    else if (rank < 16) { k = 1; base = 4;  }
    else if (rank < 36) { k = 2; base = 16; }
    else                { k = 3; base = 36; }
    int j = rank - base;
    int s = 2*k + 2;          // ring side
    int seg = j / (s - 1);
    int off = j - seg * (s - 1);
    int lo = 3 - k, hi = 4 + k;
    if      (seg == 0) { tx = lo + off; ty = lo; }
    else if (seg == 1) { tx = hi;       ty = lo + off; }
    else if (seg == 2) { tx = hi - off; ty = hi; }
    else               { tx = lo;       ty = hi - off; }
}

// ---------------- init: zbuf = +inf bits ---------------------------------------
__global__ void k_init(unsigned int* __restrict__ zbuf, int nz) {
    int i = blockIdx.x * blockDim.x + threadIdx.x;
    int stride = gridDim.x * blockDim.x;
    for (int j = i; j < nz; j += stride) zbuf[j] = 0x7F800000u;  // +inf
}

// ---------------- project vertices to NDC (u, v, z) ---------------------------
__global__ void k_project(const float* __restrict__ verts,
                          const float* __restrict__ Km,
                          const float* __restrict__ Rm,
                          const float* __restrict__ tm,
                          const float* __restrict__ dm,
                          float4* __restrict__ pv, int B, int V) {
    int i = blockIdx.x * blockDim.x + threadIdx.x;
    if (i >= B * V) return;
    int b = i / V;
    const float* R = Rm + b * 9;
    const float* K = Km + b * 9;
    const float* t = tm + b * 3;
    const float* d = dm + b * 5;
    float px = verts[3*i], py = verts[3*i+1], pz = verts[3*i+2];
    float x = R[0]*px + R[1]*py + R[2]*pz + t[0];
    float y = R[3]*px + R[4]*py + R[5]*pz + t[1];
    float z = R[6]*px + R[7]*py + R[8]*pz + t[2];
    float iz = 1.0f / (z + 1e-9f);
    float x_ = x * iz, y_ = y * iz;
    float k1 = d[0], k2 = d[1], p1 = d[2], p2 = d[3], k3 = d[4];
    float r2 = x_*x_ + y_*y_;
    float rad = 1.0f + k1*r2 + k2*r2*r2 + k3*r2*r2*r2;
    float xd = x_*rad + 2.0f*p1*x_*y_ + p2*(r2 + 2.0f*x_*x_);
    float yd = y_*rad + p1*(r2 + 2.0f*y_*y_) + 2.0f*p2*x_*y_;
    float u  = K[0]*xd + K[1]*yd + K[2];
    float vc = K[3]*xd + K[4]*yd + K[5];
    vc = 1024.0f - vc;
    u  = (u  - 512.0f) * (1.0f/512.0f);
    vc = (vc - 512.0f) * (1.0f/512.0f);
    pv[i] = make_float4(u, vc, z, 0.0f);
}

// ---------------- face setup ---------------------------------------------------
// fd[3i+0]=ca=(P0x,P0y,P1x,P1y)  fd[3i+1]=cb=(P2x,P2y,A0,A1)
// fd[3i+2]=cc=(A2, -zix, -ziy, 10-zic)   [n3 = 10 - zinv as 4th plane]
// bb=(xmn,xmx,ymn,ymx); invalid -> always-fail bbox
__global__ void k_facesetup(const int* __restrict__ faces,
                            const float4* __restrict__ pv,
                            float4* __restrict__ fd, float4* __restrict__ bb,
                            int B, int V, int F) {
    int i = blockIdx.x * blockDim.x + threadIdx.x;
    if (i >= B * F) return;
    int b = i / F;
    int i0 = faces[3*i], i1 = faces[3*i+1], i2 = faces[3*i+2];
    float4 v0 = pv[b*V + i0], v1 = pv[b*V + i1], v2 = pv[b*V + i2];
    float x0=v0.x, y0=v0.y, z0=v0.z;
    float x1=v1.x, y1=v1.y, z1=v1.z;
    float x2=v2.x, y2=v2.y, z2=v2.z;
    float denom = (y1-y2)*(x0-x2) + (x2-x1)*(y0-y2);
    bool ok = (fabsf(denom) > 1e-8f) && (z0 > 1e-8f) && (z1 > 1e-8f) && (z2 > 1e-8f);
    if (!ok) { bb[i] = make_float4(3e38f, -3e38f, 3e38f, -3e38f); return; }
    float s = (denom > 0.0f) ? 1.0f : -1.0f;
    float absd = fabsf(denom);
    float P0x = s*(y1-y2), P0y = s*(x2-x1);
    float P1x = s*(y2-y0), P1y = s*(x0-x2);
    float P2x = -(P0x + P1x), P2y = -(P0y + P1y);
    float A0 = -(P0x*x2 + P0y*y2);
    float A1 = -(P1x*x2 + P1y*y2);
    float A2 = absd - A0 - A1;
    float ia  = 1.0f / absd;
    float rz0 = ia / z0, rz1 = ia / z1, rz2 = ia / z2;
    float zix = P0x*rz0 + P1x*rz1 + P2x*rz2;
    float ziy = P0y*rz0 + P1y*rz1 + P2y*rz2;
    float zic = A0*rz0 + A1*rz1 + A2*rz2;
    fd[(size_t)i*3 + 0] = make_float4(P0x, P0y, P1x, P1y);
    fd[(size_t)i*3 + 1] = make_float4(P2x, P2y, A0, A1);
    fd[(size_t)i*3 + 2] = make_float4(A2, -zix, -ziy, 10.0f - zic);
    bb[i] = make_float4(fminf(x0, fminf(x1, x2)) - 1e-4f,
                        fmaxf(x0, fmaxf(x1, x2)) + 1e-4f,
                        fminf(y0, fminf(y1, y2)) - 1e-4f,
                        fmaxf(y0, fmaxf(y1, y2)) + 1e-4f);
}

// conservative tile-vs-face test: max of each edge plane over tile rect corners
__device__ __forceinline__ bool tile_test(const float4& ca, const float4& cb, const float4& cc,
                                          float txlo, float txhi, float tylo, float tyhi) {
    float m0 = fmaxf(ca.x*txlo, ca.x*txhi) + fmaxf(ca.y*tylo, ca.y*tyhi) + cb.z;
    float m1 = fmaxf(ca.z*txlo, ca.z*txhi) + fmaxf(ca.w*tylo, ca.w*tyhi) + cb.w;
    float m2 = fmaxf(cb.x*txlo, cb.x*txhi) + fmaxf(cb.y*tylo, cb.y*tyhi) + cc.x;
    return fminf(fminf(m0, m1), m2) >= -1e-5f;
}

// ---------------- static-stratified raster ------------------------------------
// unit = (tile-rank [center-out], batch, face-split), rank-major order so load
// is ~monotone decreasing in unit id. Block i statically takes units
// {i, half-1-i, half+i, U-1-i} (one per load-quartile, anti-correlated).
// Duplicate or skipped ids are harmless: merge is idempotent min.
// 4 waves cover the 32x32 tile (8 rows each, 4 px/lane); ballot-compact
// survivors into LDS; merge via read-filtered atomicMin (uint-monotone on
// n3 >= 0, zbuf init +inf).
__global__ __launch_bounds__(256) void k_raster(const float4* __restrict__ fd,
                                                const float4* __restrict__ bb,
                                                unsigned int* __restrict__ zbuf,
                                                int B, int F) {
    __shared__ float4 sA[257], sB[257], sC[257];
    __shared__ int s_cnt[4];
    int tid = threadIdx.x, lane = tid & 63, wave = tid >> 6;
    int per = B * NSPLIT;
    int nitems = TILES * per;
    int half = nitems >> 1;
    int bi = blockIdx.x;
    int ids[4] = { bi, half - 1 - bi, half + bi, nitems - 1 - bi };

    for (int q = 0; q < 4; ++q) {
        int wi = ids[q];
        if (wi < 0 || wi >= nitems) continue;
        int rank = wi / per;
        int rem  = wi - rank * per;
        int b  = rem / NSPLIT;
        int sp = rem - b * NSPLIT;
        int tx, ty;
        rank_to_tile(rank, tx, ty);
        int row = ty*TH + wave*8 + (lane >> 3);
        int col = tx*TW + (lane & 7) * 4;
        float yp = ndc(row);
        float xp[4];
        #pragma unroll
        for (int j = 0; j < 4; ++j) xp[j] = ndc(col + j);
        float txlo = ndc(tx*TW), txhi = ndc(tx*TW + TW - 1);
        float tylo = ndc(ty*TH), tyhi = ndc(ty*TH + TH - 1);
        int f_begin = (sp * F) / NSPLIT, f_end = ((sp+1) * F) / NSPLIT;
        float m[4] = {BIGF, BIGF, BIGF, BIGF};

        for (int g0 = f_begin; g0 < f_end; g0 += 256) {
            int f = g0 + tid;
            bool pass = false;
            float4 ra, rb, rc;
            if (f < f_end) {
                size_t gi = (size_t)b * F + f;
                float4 box = bb[gi];
                pass = !(box.x > txhi || box.y < txlo || box.z > tyhi || box.w < tylo);
                if (pass) {
                    ra = fd[gi*3]; rb = fd[gi*3+1]; rc = fd[gi*3+2];
                    pass = tile_test(ra, rb, rc, txlo, txhi, tylo, tyhi);
                }
            }
            unsigned long long mk = __ballot(pass);
            int prefix = __popcll(mk & ((1ull << lane) - 1ull));
            if (lane == 0) s_cnt[wave] = __popcll(mk);
            __syncthreads();
            int base = 0;
            #pragma unroll
            for (int w = 0; w < 4; ++w) base += (w < wave) ? s_cnt[w] : 0;
            int total = s_cnt[0] + s_cnt[1] + s_cnt[2] + s_cnt[3];
            if (pass) {
                int slot = base + prefix;
                sA[slot] = ra;
                sB[slot] = rb;
                sC[slot] = rc;
            }
            __syncthreads();
            if (total > 0) {
                float4 ca = sA[0], cb = sB[0], cc = sC[0];
                for (int i = 0; i < total; ++i) {
                    float4 na = sA[i+1], nb = sB[i+1], nc = sC[i+1];  // prefetch
                    float e0 = fmaf(ca.y, yp, cb.z);
                    float e1 = fmaf(ca.w, yp, cb.w);
                    float e2 = fmaf(cb.y, yp, cc.x);
                    float e3 = fmaf(cc.z, yp, cc.w);
                    #pragma unroll
                    for (int j = 0; j < 4; ++j) {
                        float n0 = fmaf(ca.x, xp[j], e0);
                        float n1 = fmaf(ca.z, xp[j], e1);
                        float n2 = fmaf(cb.x, xp[j], e2);
                        float n3 = fmaf(cc.y, xp[j], e3);
                        float mn = fminf(fminf(fminf(n0, n1), n2), n3);
                        m[j] = fminf(m[j], (mn >= 0.0f) ? n3 : BIGF);
                    }
                    ca = na; cb = nb; cc = nc;
                }
            }
            __syncthreads();
        }
        size_t zo = (size_t)b * (IMG*IMG) + (size_t)row * IMG + col;
        #pragma unroll
        for (int j = 0; j < 4; ++j) {
            if (m[j] < 9.99f) {
                unsigned int mv = __float_as_uint(m[j]);
                unsigned int cv = zbuf[zo + j];          // racy read: stale only costs a redundant atomic
                if (mv < cv) atomicMin(&zbuf[zo + j], mv);
            }
        }
    }
}

// ---------------- resolve: depth = 1/(10-m), row flip -------------------------
__global__ void k_resolve(const unsigned int* __restrict__ zbuf, float* __restrict__ out, int B) {
    int i = blockIdx.x * blockDim.x + threadIdx.x;
    int n = B * IMG * IMG;
    if (i >= n) return;
    int b = i / (IMG*IMG);
    int rem = i - b * (IMG*IMG);
    int r = rem >> 8, c = rem & 255;
    unsigned int u = zbuf[(size_t)b*(IMG*IMG) + (IMG-1-r)*IMG + c];
    float m = __uint_as_float(u);
    out[i] = (m < 9.99f) ? 1.0f / (10.0f - m) : 100.0f;
}

// ---------------- fallback: brute row-stripe direct (tiny ws only) ------------
__global__ __launch_bounds__(256) void k_brute(const float4* __restrict__ fd,
                                               const float4* __restrict__ bb,
                                               float* __restrict__ out, int B, int F) {
    int bid = blockIdx.x;
    int stripe = bid % 64, b = bid / 64;
    int tid = threadIdx.x, lane = tid & 63, wave = tid >> 6;
    int row = stripe * 4 + wave, colb = lane * 4;
    float yp = ndc(row);
    float xp[4]; float m[4];
    #pragma unroll
    for (int j = 0; j < 4; ++j) { xp[j] = ndc(colb + j); m[j] = BIGF; }
    const float4* fbb = bb + (size_t)b * F;
    const float4* ffd = fd + (size_t)b * F * 3;
    for (int f = 0; f < F; ++f) {
        float4 box = fbb[f];
        if (box.z > yp || box.w < yp) continue;
        float4 ca = ffd[3*f], cb = ffd[3*f+1], cc = ffd[3*f+2];
        float e0 = fmaf(ca.y, yp, cb.z);
        float e1 = fmaf(ca.w, yp, cb.w);
        float e2 = fmaf(cb.y, yp, cc.x);
        float e3 = fmaf(cc.z, yp, cc.w);
        #pragma unroll
        for (int j = 0; j < 4; ++j) {
            float n0 = fmaf(ca.x, xp[j], e0);
            float n1 = fmaf(ca.z, xp[j], e1);
            float n2 = fmaf(cb.x, xp[j], e2);
            float n3 = fmaf(cc.y, xp[j], e3);
            float mn = fminf(fminf(fminf(n0, n1), n2), n3);
            m[j] = fminf(m[j], (mn >= 0.0f) ? n3 : BIGF);
        }
    }
    size_t o = (size_t)b*(IMG*IMG) + (size_t)(IMG-1-row)*IMG + colb;
    float4 r;
    r.x = (m[0] < 9.99f) ? 1.0f/(10.0f-m[0]) : 100.0f;
    r.y = (m[1] < 9.99f) ? 1.0f/(10.0f-m[1]) : 100.0f;
    r.z = (m[2] < 9.99f) ? 1.0f/(10.0f-m[2]) : 100.0f;
    r.w = (m[3] < 9.99f) ? 1.0f/(10.0f-m[3]) : 100.0f;
    *(float4*)(out + o) = r;
}

extern "C" void kernel_launch(void* const* d_in, const int* in_sizes, int n_in,
                              void* d_out, int out_size, void* d_ws, size_t ws_size,
                              hipStream_t stream) {
    const float* verts = (const float*)d_in[0];
    const int*   faces = (const int*)d_in[1];
    const float* Km    = (const float*)d_in[2];
    const float* Rm    = (const float*)d_in[3];
    const float* tm    = (const float*)d_in[4];
    const float* dm    = (const float*)d_in[5];
    float* out = (float*)d_out;

    int B = in_sizes[2] / 9;
    int V = in_sizes[0] / (3 * B);
    int F = in_sizes[1] / (3 * B);
    int nz = B * IMG * IMG;

    char* ws = (char*)d_ws;
    size_t al = 255;
    size_t o_pv  = 0;
    size_t o_fd  = (o_pv + (size_t)B*V*16 + al) & ~al;
    size_t o_bb  = (o_fd + (size_t)B*F*48 + al) & ~al;
    size_t o_zb  = (o_bb + (size_t)B*F*16 + al) & ~al;
    size_t need  = o_zb + (size_t)nz*4;
    size_t need_brute = o_zb;

    float4* pv  = (float4*)(ws + o_pv);
    float4* fd  = (float4*)(ws + o_fd);
    float4* bbp = (float4*)(ws + o_bb);
    unsigned int* zb = (unsigned int*)(ws + o_zb);

    const int thr = 256;
    k_project<<<(B*V + thr-1)/thr, thr, 0, stream>>>(verts, Km, Rm, tm, dm, pv, B, V);
    if (ws_size >= need) {
        k_init<<<256, thr, 0, stream>>>(zb, nz);
        k_facesetup<<<(B*F + thr-1)/thr, thr, 0, stream>>>(faces, pv, fd, bbp, B, V, F);
        k_raster<<<RBLOCKS, thr, 0, stream>>>(fd, bbp, zb, B, F);
        k_resolve<<<(nz + thr-1)/thr, thr, 0, stream>>>(zb, out, B);
    } else if (ws_size >= need_brute) {
        k_facesetup<<<(B*F + thr-1)/thr, thr, 0, stream>>>(faces, pv, fd, bbp, B, V, F);
        k_brute<<<B*64, thr, 0, stream>>>(fd, bbp, out, B, F);
    }
}